// Round 17
// baseline (494.115 us; speedup 1.0000x reference)
//
#include <hip/hip_runtime.h>
#include <stdint.h>

// AR(12) rollout, feed-forward/feedback decomposition.
// y_{t+1} = F_{t+1} + sum_{j=0..t-1} W_{12-t+j} . y_{j+1}
// R16: BUBBLE-FILL MERGE. F products for step t depend only on prep, so they
// ride inside launch L(t) together with step t's FB chunks. Every L(t) then
// carries a constant 12.9 GF (FB: 4t chunks K=512; F: 2(12-t) chunks K=1024,
// heavy-first), eliminating the standalone ~100us F launch and filling the
// small-t FB launches that previously ran latency-bound on an idle GPU.
// gemm_body = R13's proven depth-2 counted-vmcnt, 3 buffers, 48KB, 3 blk/CU.

typedef _Float16 f16x8 __attribute__((ext_vector_type(8)));
typedef float    f32x4 __attribute__((ext_vector_type(4)));

#define B_ 128
#define N_ 2048
#define P_ 12
#define K_ (P_*N_)          // 24576
#define NT 16               // N-tiles of 128
#define NKP (K_/64)         // 384 BK64 W-tiles per nt column

#define WPK_BYTES    ((size_t)NT*NKP*16384)    // 100,663,296 (fp16, tiled)
#define H_SLOT_BYTES ((size_t)B_*N_*2)         // 524,288 per window slot
#define H_BYTES      (23*H_SLOT_BYTES)         // 12,058,624
#define CH_BYTES     ((size_t)B_*N_*2)         // one partial chunk (fp16)
#define PF_BYTES     (156*CH_BYTES)            // 81,788,928 (78 products x 2 subs)
#define PFB_BYTES    (44*CH_BYTES)             // 23,068,672
#define WS_NEEDED    (WPK_BYTES + H_BYTES + PF_BYTES + PFB_BYTES)  // ~218 MB

// Scale exponents for y_{t+1} (t=0..10): e = round(7.29 + 5.50*t) from the
// variance recursion sigma(y_1)=sqrt(24576), growth sqrt(2048) per step.
__device__ __constant__ int E_TAB[11] = {7, 13, 18, 24, 29, 35, 40, 46, 51, 57, 62};

__device__ __forceinline__ float pow2f(int e) {      // exact 2^e, |e| < 127
    return __uint_as_float((uint32_t)(127 + e) << 23);
}

union F16x8 { _Float16 h[8]; uint4 q; };
union F16x4v { _Float16 h[4]; uint2 q; };

// ---- H (window) layout (R1-R15 proven): [slot][kblk=k/32][b][k%32] fp16 with
// XOR swizzle per 8KB tile: byte = (b*64 + (k&31)*2) ^ ((b&7)<<4).
__device__ __forceinline__ uint32_t h_off(int slot, int b, int k) {
    uint32_t t = (uint32_t)((b << 6) + ((k & 31) << 1)) ^ (uint32_t)((b & 7) << 4);
    return (uint32_t)slot * (uint32_t)H_SLOT_BYTES + (uint32_t)(k >> 5) * 8192u + t;
}
// ---- Wp (B) layout: tile(nt, pk) = 16 KB covering BK=64 x BN=128 (proven) ----
__device__ __forceinline__ size_t w_tile_base(int nt, int pk) {
    return ((size_t)nt * NKP + (size_t)pk) * 16384;
}

// ---------------- prep: x->H (blocks 0..127), W->Wp (128..6271) ----------------
__global__ void prep_all(const float* __restrict__ x, const float* __restrict__ W,
                         char* __restrict__ Wp, char* __restrict__ H)
{
    __shared__ float tile[128][68];   // +4 pad
    int bid = blockIdx.x, t = threadIdx.x;
    if (bid < 128) {
        int tg = bid * 256 + t;                 // 32768 threads: (b, n-octet)
        int b = tg >> 8;
        int n0 = (tg & 255) << 3;
        const float4* s4 = (const float4*)(x + ((size_t)b * N_ + n0) * P_);
        float4 tmp[24];
        #pragma unroll
        for (int i2 = 0; i2 < 24; ++i2) tmp[i2] = s4[i2];
        #pragma unroll
        for (int p = 0; p < 12; ++p) {
            F16x8 o;
            #pragma unroll
            for (int q = 0; q < 8; ++q) {
                int fi = q * 12 + p;            // compile-time constant
                float4 blk = tmp[fi >> 2];
                float f = ((fi & 3) == 0) ? blk.x : ((fi & 3) == 1) ? blk.y : ((fi & 3) == 2) ? blk.z : blk.w;
                o.h[q] = (_Float16)f;
            }
            *(uint4*)(H + h_off(p, b, n0)) = o.q;   // 16B-aligned under swizzle
        }
        return;
    }
    int u = bid - 128;                          // 0..6143 = 16 nt x 384 pk
    int nt = u / NKP, pk = u % NKP;
    int i  = pk >> 5;                           // W slice 0..11
    int k0 = (pk & 31) << 6;                    // k-in-slice
    int j0 = nt << 7;
    #pragma unroll
    for (int pass = 0; pass < 8; ++pass) {      // coalesced fp32 reads along k
        int jl = pass * 16 + (t >> 4);
        int kq = (t & 15) * 4;
        float4 v = *(const float4*)(W + ((size_t)i * N_ + (j0 + jl)) * N_ + k0 + kq);
        tile[jl][kq + 0] = v.x; tile[jl][kq + 1] = v.y;
        tile[jl][kq + 2] = v.z; tile[jl][kq + 3] = v.w;
    }
    __syncthreads();
    int ksub = t >> 7, c = t & 127;
    char* base = Wp + w_tile_base(nt, pk) + (ksub << 13);
    #pragma unroll
    for (int ko = 0; ko < 4; ++ko) {
        F16x8 o;
        #pragma unroll
        for (int q = 0; q < 8; ++q) o.h[q] = (_Float16)tile[c][ksub * 32 + ko * 8 + q];
        uint32_t off = (uint32_t)((c << 6) + (ko << 4)) ^ (uint32_t)((c & 7) << 4);
        *(uint4*)(base + off) = o.q;
    }
}

// ---------------- R13 GEMM body (unchanged): depth-2 counted-vmcnt, 3 bufs ----------------
__device__ __forceinline__ void gemm_body(
        const char* __restrict__ Wp, const char* __restrict__ H,
        _Float16* __restrict__ part, char* ldsAB,
        int nt, int pk0, int slot, int k0, int nph)
{
    const int tid  = threadIdx.x;
    const int lane = tid & 63;
    const int wv   = tid >> 6;
    const int wr   = wv >> 1;                   // M half
    const int wc   = wv & 1;                    // N half
    const int l15  = lane & 15;
    const int ko   = lane >> 4;                 // k-octet 0..3
    const int jbase = (nt << 7) + (wc << 6) + l15;

    uint32_t aoff[4], boff[4];
    #pragma unroll
    for (int m = 0; m < 4; ++m) {
        int row = (wr << 6) + (m << 4) + l15;
        aoff[m] = (uint32_t)((row << 6) + (ko << 4)) ^ (uint32_t)((row & 7) << 4);
    }
    #pragma unroll
    for (int nf = 0; nf < 4; ++nf) {
        int c = (wc << 6) + (nf << 4) + l15;
        boff[nf] = (uint32_t)((c << 6) + (ko << 4)) ^ (uint32_t)((c & 7) << 4);
    }

    auto stage = [&](int buf, int ph) {         // A 8KB + B 8KB, 4 insts/thread
        int k = k0 + (ph << 5);
        const char* sA = H + (size_t)slot * H_SLOT_BYTES + (uint32_t)((k >> 5) << 13);
        const char* sB = Wp + w_tile_base(nt, pk0 + (ph >> 1)) + (uint32_t)((ph & 1) << 13);
        #pragma unroll
        for (int j = 0; j < 2; ++j) {
            uint32_t o = (uint32_t)(j << 12) + (uint32_t)(tid << 4);
            uint32_t d = (uint32_t)(j << 12) + (uint32_t)(wv << 10);
            __builtin_amdgcn_global_load_lds(
                (const __attribute__((address_space(1))) void*)(sA + o),
                (__attribute__((address_space(3))) void*)(ldsAB + buf * 16384 + d), 16, 0, 0);
            __builtin_amdgcn_global_load_lds(
                (const __attribute__((address_space(1))) void*)(sB + o),
                (__attribute__((address_space(3))) void*)(ldsAB + buf * 16384 + 8192 + d), 16, 0, 0);
        }
    };

    f32x4 acc[4][4];
    #pragma unroll
    for (int m = 0; m < 4; ++m)
        #pragma unroll
        for (int n = 0; n < 4; ++n) acc[m][n] = (f32x4){0.f, 0.f, 0.f, 0.f};

    stage(0, 0);
    stage(1, 1);
    asm volatile("s_waitcnt vmcnt(4) lgkmcnt(0)" ::: "memory");
    __builtin_amdgcn_s_barrier();

    int cur = 0;
    #pragma unroll 1
    for (int ph = 0; ph < nph; ++ph) {
        int nxt2 = cur + 2; if (nxt2 >= 3) nxt2 -= 3;
        if (ph + 2 < nph) stage(nxt2, ph + 2);
        const char* lA = ldsAB + cur * 16384;
        const char* lB = lA + 8192;
        f16x8 ah[4], bf[4];
        #pragma unroll
        for (int m = 0; m < 4; ++m) ah[m] = *(const f16x8*)(lA + aoff[m]);
        #pragma unroll
        for (int nf = 0; nf < 4; ++nf) bf[nf] = *(const f16x8*)(lB + boff[nf]);
        #pragma unroll
        for (int m = 0; m < 4; ++m)
            #pragma unroll
            for (int nf = 0; nf < 4; ++nf)
                acc[m][nf] = __builtin_amdgcn_mfma_f32_16x16x32_f16(ah[m], bf[nf], acc[m][nf], 0, 0, 0);
        if (ph + 1 < nph) {
            if (ph + 2 < nph) asm volatile("s_waitcnt vmcnt(4) lgkmcnt(0)" ::: "memory");
            else              asm volatile("s_waitcnt vmcnt(0) lgkmcnt(0)" ::: "memory");
            __builtin_amdgcn_s_barrier();
        }
        ++cur; if (cur == 3) cur = 0;
    }

    const int r0 = (lane >> 4) << 2;
    _Float16* pb = part + ((size_t)((wr << 6) + r0)) * N_ + jbase;
    #pragma unroll
    for (int m = 0; m < 4; ++m)
        #pragma unroll
        for (int n = 0; n < 4; ++n)
            #pragma unroll
            for (int r = 0; r < 4; ++r)
                pb[(size_t)(m * 16 + r) * N_ + n * 16] = (_Float16)acc[m][n][r];
}

// ---------------- L(t): merged launch -- F half-products (heavy, first) + FB chunks ----------------
// grid = (2*(12-t) + 4*t) * 16 blocks; nt = bid&15 (XCD-stable), c = bid>>4.
// c <  2*(12-t): F half-chunk: f=c>>1, sub=c&1 -> W_f . x_{t+f} over K half sub
//   (nph=32, K=1024), dest pF[(baseT(t)+f)*2+sub]. Depends only on prep.
// c >= 2*(12-t): FB chunk cf: jj=cf>>2, sub=cf&3 -> W_{12-t+jj} . y_{jj+1}
//   K=512 sub-chunk (nph=16), dest pFB[cf]. Depends on reduce(t-1).
__global__ __launch_bounds__(256, 3) void gemm_mix(
        const char* __restrict__ Wp, const char* __restrict__ H,
        _Float16* __restrict__ pF, _Float16* __restrict__ pFB, int t)
{
    __shared__ alignas(16) char ldsAB[3 * 16384];
    const int nt = blockIdx.x & 15;
    const int c  = blockIdx.x >> 4;
    const int nF2 = 2 * (12 - t);
    if (c < nF2) {
        int f = c >> 1, sub = c & 1;
        int baseT = t * 12 - t * (t - 1) / 2;
        gemm_body(Wp, H, pF + (size_t)((baseT + f) * 2 + sub) * (CH_BYTES / 2), ldsAB,
                  nt, f * 32 + sub * 16, t + f, sub * 1024, 32);
    } else {
        int cf = c - nF2;
        int jj = cf >> 2, sub = cf & 3;
        int i = 12 - t + jj;                    // W slice index
        gemm_body(Wp, H, pFB + (size_t)cf * (CH_BYTES / 2), ldsAB,
                  nt, i * 32 + sub * 8, 12 + jj, sub * 512, 16);
    }
}

// ---------------- reduce step t: y_{t+1} = sum F-chunks + scaled fb-chunks ----------------
__global__ void reduce_step(const _Float16* __restrict__ pF, const _Float16* __restrict__ pFB,
                            float* __restrict__ out, char* __restrict__ H, int t)
{
    int tid = blockIdx.x * 256 + threadIdx.x;   // 65536 threads: (b, n-quad)
    int b = tid >> 9;
    int n0 = (tid & 511) << 2;
    const size_t eo = (size_t)b * N_ + n0;
    float s0 = 0.f, s1 = 0.f, s2 = 0.f, s3 = 0.f;
    int base2 = (t * 12 - t * (t - 1) / 2) * 2;
    int nF2 = 2 * (12 - t);
    #pragma unroll 4
    for (int f = 0; f < nF2; ++f) {             // F half-chunks: scale 1 (x domain)
        F16x4v p;
        p.q = *(const uint2*)(pF + (size_t)(base2 + f) * (CH_BYTES / 2) + eo);
        s0 += (float)p.h[0]; s1 += (float)p.h[1];
        s2 += (float)p.h[2]; s3 += (float)p.h[3];
    }
    #pragma unroll 4
    for (int c = 0; c < 4 * t; ++c) {           // fb chunks: scale 2^E[j]
        float sc = pow2f(E_TAB[c >> 2]);
        F16x4v p;
        p.q = *(const uint2*)(pFB + (size_t)c * (CH_BYTES / 2) + eo);
        s0 += (float)p.h[0] * sc; s1 += (float)p.h[1] * sc;
        s2 += (float)p.h[2] * sc; s3 += (float)p.h[3] * sc;
    }
    float* ob = out + eo * P_ + t;
    ob[0 * P_] = s0; ob[1 * P_] = s1; ob[2 * P_] = s2; ob[3 * P_] = s3;
    if (t < 11) {                               // store y_{t+1} scaled by 2^-e
        float ds = pow2f(-E_TAB[t]);
        F16x4v o;
        o.h[0] = (_Float16)(s0 * ds); o.h[1] = (_Float16)(s1 * ds);
        o.h[2] = (_Float16)(s2 * ds); o.h[3] = (_Float16)(s3 * ds);
        *(uint2*)(H + h_off(12 + t, b, n0)) = o.q;   // 8B-aligned under swizzle
    }
}

// ---------------- insurance: naive fp32 path if workspace is too small ----------------
__global__ void naive_step(const float* __restrict__ x, const float* __restrict__ W,
                           float* __restrict__ out, int t)
{
    int tid = blockIdx.x * 256 + threadIdx.x;   // 262144 threads: (b, j)
    int b = tid >> 11;
    int j = tid & (N_ - 1);
    float acc = 0.f;
    for (int i = 0; i < 12; ++i) {
        int g = t + i;
        const float* src = (g < 12) ? (x   + (size_t)b * (N_ * 12) + g)
                                    : (out + (size_t)b * (N_ * 12) + (g - 12));
        const float* wr = W + ((size_t)i * N_ + j) * N_;
        for (int k = 0; k < N_; ++k)
            acc += wr[k] * src[(size_t)k * 12];
    }
    out[((size_t)b * N_ + j) * 12 + t] = acc;
}

extern "C" void kernel_launch(void* const* d_in, const int* in_sizes, int n_in,
                              void* d_out, int out_size, void* d_ws, size_t ws_size,
                              hipStream_t stream)
{
    const float* x = (const float*)d_in[0];
    const float* W = (const float*)d_in[1];
    float* out = (float*)d_out;

    if (ws_size < WS_NEEDED) {                  // fallback: correct but slow
        for (int t = 0; t < 12; ++t)
            naive_step<<<1024, 256, 0, stream>>>(x, W, out, t);
        return;
    }

    char* Wp = (char*)d_ws;
    char* H  = Wp + WPK_BYTES;
    _Float16* pF  = (_Float16*)(H + H_BYTES);
    _Float16* pFB = (_Float16*)(H + H_BYTES + PF_BYTES);

    prep_all<<<6272, 256, 0, stream>>>(x, W, Wp, H);
    for (int t = 0; t < 12; ++t) {
        int grid = (2 * (12 - t) + 4 * t) * 16;         // (24+2t)*16
        gemm_mix<<<grid, 256, 0, stream>>>(Wp, H, pF, pFB, t);
        reduce_step<<<256, 256, 0, stream>>>(pF, pFB, out, H, t);
    }
}

// Round 18
// 443.428 us; speedup vs baseline: 1.1143x; 1.1143x over previous
//
#include <hip/hip_runtime.h>
#include <stdint.h>

// AR(12) rollout, feed-forward/feedback decomposition.
// y_{t+1} = F_{t+1} + sum_{j=0..t-1} W_{12-t+j} . y_{j+1}
// FINAL (= R15, best measured 443.9us): R13's depth-2 counted-vmcnt GEMM body
// (3 LDS buffers, 48KB, 3 blocks/CU) for FB; multi-slot gemm_F2 (one staged B
// vs two x-slots). fp16 single-product numerics with exact power-of-2 slot
// scaling; fp16 L2-resident partials. absmax 4.6e18 (5.3x threshold margin).

typedef _Float16 f16x8 __attribute__((ext_vector_type(8)));
typedef float    f32x4 __attribute__((ext_vector_type(4)));

#define B_ 128
#define N_ 2048
#define P_ 12
#define K_ (P_*N_)          // 24576
#define NT 16               // N-tiles of 128
#define NKP (K_/64)         // 384 BK64 W-tiles per nt column

#define WPK_BYTES    ((size_t)NT*NKP*16384)    // 100,663,296 (fp16, tiled)
#define H_SLOT_BYTES ((size_t)B_*N_*2)         // 524,288 per window slot
#define H_BYTES      (23*H_SLOT_BYTES)         // 12,058,624
#define CH_BYTES     ((size_t)B_*N_*2)         // one partial chunk (fp16)
#define PF_BYTES     (78*CH_BYTES)             // 40,894,464
#define PFB_BYTES    (44*CH_BYTES)             // 23,068,672
#define WS_NEEDED    (WPK_BYTES + H_BYTES + PF_BYTES + PFB_BYTES)  // ~177 MB

// Scale exponents for y_{t+1} (t=0..10): e = round(7.29 + 5.50*t) from the
// variance recursion sigma(y_1)=sqrt(24576), growth sqrt(2048) per step.
__device__ __constant__ int E_TAB[11] = {7, 13, 18, 24, 29, 35, 40, 46, 51, 57, 62};

__device__ __forceinline__ float pow2f(int e) {      // exact 2^e, |e| < 127
    return __uint_as_float((uint32_t)(127 + e) << 23);
}

union F16x8 { _Float16 h[8]; uint4 q; };
union F16x4v { _Float16 h[4]; uint2 q; };

// ---- H (window) layout (R1-R15 proven): [slot][kblk=k/32][b][k%32] fp16 with
// XOR swizzle per 8KB tile: byte = (b*64 + (k&31)*2) ^ ((b&7)<<4).
__device__ __forceinline__ uint32_t h_off(int slot, int b, int k) {
    uint32_t t = (uint32_t)((b << 6) + ((k & 31) << 1)) ^ (uint32_t)((b & 7) << 4);
    return (uint32_t)slot * (uint32_t)H_SLOT_BYTES + (uint32_t)(k >> 5) * 8192u + t;
}
// ---- Wp (B) layout: tile(nt, pk) = 16 KB covering BK=64 x BN=128 (proven) ----
__device__ __forceinline__ size_t w_tile_base(int nt, int pk) {
    return ((size_t)nt * NKP + (size_t)pk) * 16384;
}

// ---------------- prep: x->H (blocks 0..127), W->Wp (128..6271) ----------------
__global__ void prep_all(const float* __restrict__ x, const float* __restrict__ W,
                         char* __restrict__ Wp, char* __restrict__ H)
{
    __shared__ float tile[128][68];   // +4 pad
    int bid = blockIdx.x, t = threadIdx.x;
    if (bid < 128) {
        int tg = bid * 256 + t;                 // 32768 threads: (b, n-octet)
        int b = tg >> 8;
        int n0 = (tg & 255) << 3;
        const float4* s4 = (const float4*)(x + ((size_t)b * N_ + n0) * P_);
        float4 tmp[24];
        #pragma unroll
        for (int i2 = 0; i2 < 24; ++i2) tmp[i2] = s4[i2];
        #pragma unroll
        for (int p = 0; p < 12; ++p) {
            F16x8 o;
            #pragma unroll
            for (int q = 0; q < 8; ++q) {
                int fi = q * 12 + p;            // compile-time constant
                float4 blk = tmp[fi >> 2];
                float f = ((fi & 3) == 0) ? blk.x : ((fi & 3) == 1) ? blk.y : ((fi & 3) == 2) ? blk.z : blk.w;
                o.h[q] = (_Float16)f;
            }
            *(uint4*)(H + h_off(p, b, n0)) = o.q;   // 16B-aligned under swizzle
        }
        return;
    }
    int u = bid - 128;                          // 0..6143 = 16 nt x 384 pk
    int nt = u / NKP, pk = u % NKP;
    int i  = pk >> 5;                           // W slice 0..11
    int k0 = (pk & 31) << 6;                    // k-in-slice
    int j0 = nt << 7;
    #pragma unroll
    for (int pass = 0; pass < 8; ++pass) {      // coalesced fp32 reads along k
        int jl = pass * 16 + (t >> 4);
        int kq = (t & 15) * 4;
        float4 v = *(const float4*)(W + ((size_t)i * N_ + (j0 + jl)) * N_ + k0 + kq);
        tile[jl][kq + 0] = v.x; tile[jl][kq + 1] = v.y;
        tile[jl][kq + 2] = v.z; tile[jl][kq + 3] = v.w;
    }
    __syncthreads();
    int ksub = t >> 7, c = t & 127;
    char* base = Wp + w_tile_base(nt, pk) + (ksub << 13);
    #pragma unroll
    for (int ko = 0; ko < 4; ++ko) {
        F16x8 o;
        #pragma unroll
        for (int q = 0; q < 8; ++q) o.h[q] = (_Float16)tile[c][ksub * 32 + ko * 8 + q];
        uint32_t off = (uint32_t)((c << 6) + (ko << 4)) ^ (uint32_t)((c & 7) << 4);
        *(uint4*)(base + off) = o.q;
    }
}

// ---------------- R13 GEMM body (proven): depth-2 counted-vmcnt, 3 bufs ----------------
__device__ __forceinline__ void gemm_body(
        const char* __restrict__ Wp, const char* __restrict__ H,
        _Float16* __restrict__ part, char* ldsAB,
        int nt, int pk0, int slot, int k0, int nph)
{
    const int tid  = threadIdx.x;
    const int lane = tid & 63;
    const int wv   = tid >> 6;
    const int wr   = wv >> 1;                   // M half
    const int wc   = wv & 1;                    // N half
    const int l15  = lane & 15;
    const int ko   = lane >> 4;                 // k-octet 0..3
    const int jbase = (nt << 7) + (wc << 6) + l15;

    uint32_t aoff[4], boff[4];
    #pragma unroll
    for (int m = 0; m < 4; ++m) {
        int row = (wr << 6) + (m << 4) + l15;
        aoff[m] = (uint32_t)((row << 6) + (ko << 4)) ^ (uint32_t)((row & 7) << 4);
    }
    #pragma unroll
    for (int nf = 0; nf < 4; ++nf) {
        int c = (wc << 6) + (nf << 4) + l15;
        boff[nf] = (uint32_t)((c << 6) + (ko << 4)) ^ (uint32_t)((c & 7) << 4);
    }

    auto stage = [&](int buf, int ph) {         // A 8KB + B 8KB, 4 insts/thread
        int k = k0 + (ph << 5);
        const char* sA = H + (size_t)slot * H_SLOT_BYTES + (uint32_t)((k >> 5) << 13);
        const char* sB = Wp + w_tile_base(nt, pk0 + (ph >> 1)) + (uint32_t)((ph & 1) << 13);
        #pragma unroll
        for (int j = 0; j < 2; ++j) {
            uint32_t o = (uint32_t)(j << 12) + (uint32_t)(tid << 4);
            uint32_t d = (uint32_t)(j << 12) + (uint32_t)(wv << 10);
            __builtin_amdgcn_global_load_lds(
                (const __attribute__((address_space(1))) void*)(sA + o),
                (__attribute__((address_space(3))) void*)(ldsAB + buf * 16384 + d), 16, 0, 0);
            __builtin_amdgcn_global_load_lds(
                (const __attribute__((address_space(1))) void*)(sB + o),
                (__attribute__((address_space(3))) void*)(ldsAB + buf * 16384 + 8192 + d), 16, 0, 0);
        }
    };

    f32x4 acc[4][4];
    #pragma unroll
    for (int m = 0; m < 4; ++m)
        #pragma unroll
        for (int n = 0; n < 4; ++n) acc[m][n] = (f32x4){0.f, 0.f, 0.f, 0.f};

    stage(0, 0);
    stage(1, 1);
    asm volatile("s_waitcnt vmcnt(4) lgkmcnt(0)" ::: "memory");
    __builtin_amdgcn_s_barrier();

    int cur = 0;
    #pragma unroll 1
    for (int ph = 0; ph < nph; ++ph) {
        int nxt2 = cur + 2; if (nxt2 >= 3) nxt2 -= 3;
        if (ph + 2 < nph) stage(nxt2, ph + 2);
        const char* lA = ldsAB + cur * 16384;
        const char* lB = lA + 8192;
        f16x8 ah[4], bf[4];
        #pragma unroll
        for (int m = 0; m < 4; ++m) ah[m] = *(const f16x8*)(lA + aoff[m]);
        #pragma unroll
        for (int nf = 0; nf < 4; ++nf) bf[nf] = *(const f16x8*)(lB + boff[nf]);
        #pragma unroll
        for (int m = 0; m < 4; ++m)
            #pragma unroll
            for (int nf = 0; nf < 4; ++nf)
                acc[m][nf] = __builtin_amdgcn_mfma_f32_16x16x32_f16(ah[m], bf[nf], acc[m][nf], 0, 0, 0);
        if (ph + 1 < nph) {
            if (ph + 2 < nph) asm volatile("s_waitcnt vmcnt(4) lgkmcnt(0)" ::: "memory");
            else              asm volatile("s_waitcnt vmcnt(0) lgkmcnt(0)" ::: "memory");
            __builtin_amdgcn_s_barrier();
        }
        ++cur; if (cur == 3) cur = 0;
    }

    const int r0 = (lane >> 4) << 2;
    _Float16* pb = part + ((size_t)((wr << 6) + r0)) * N_ + jbase;
    #pragma unroll
    for (int m = 0; m < 4; ++m)
        #pragma unroll
        for (int n = 0; n < 4; ++n)
            #pragma unroll
            for (int r = 0; r < 4; ++r)
                pb[(size_t)(m * 16 + r) * N_ + n * 16] = (_Float16)acc[m][n][r];
}

// ---------------- F2: multi-slot F -- one staged B vs TWO x-slots ----------------
// 42 (j,g) pairs x 16 nt = 672 blocks; pair (j,g) covers slots s0=j+2g, s0+1.
// LDS/buffer: A0 8KB | A1 8KB | B 8KB = 24KB; 3 buffers = 72KB (2 blocks/CU).
// Stage = 6 insts/thread -> counted waits vmcnt(6)/0 (R13 discipline).
__global__ __launch_bounds__(256, 2) void gemm_F2(
        const char* __restrict__ Wp, const char* __restrict__ H,
        _Float16* __restrict__ pF)
{
    __shared__ alignas(16) char ldsAB[3 * 24576];
    const int tid  = threadIdx.x;
    const int lane = tid & 63;
    const int wv   = tid >> 6;
    const int wr   = wv >> 1;
    const int wc   = wv & 1;
    const int l15  = lane & 15;
    const int ko   = lane >> 4;
    const int nt   = blockIdx.x & 15;           // low bits -> stable nt->XCD
    int pair = blockIdx.x >> 4;                 // 0..41
    int j = 0;
    #pragma unroll 1
    for (int jj = 0; jj < 12; ++jj) {           // decode (j, g): c_j = ceil((12-jj)/2)
        int cj = (12 - jj + 1) >> 1;
        if (pair < cj) { j = jj; break; }
        pair -= cj;
    }
    const int s0 = j + 2 * pair;                // first slot
    const int two = (s0 + 1 <= 11);             // second slot valid?
    const int pk0 = j * 32;
    const int jbase = (nt << 7) + (wc << 6) + l15;

    uint32_t aoff[4], boff[4];
    #pragma unroll
    for (int m = 0; m < 4; ++m) {
        int row = (wr << 6) + (m << 4) + l15;
        aoff[m] = (uint32_t)((row << 6) + (ko << 4)) ^ (uint32_t)((row & 7) << 4);
    }
    #pragma unroll
    for (int nf = 0; nf < 4; ++nf) {
        int c = (wc << 6) + (nf << 4) + l15;
        boff[nf] = (uint32_t)((c << 6) + (ko << 4)) ^ (uint32_t)((c & 7) << 4);
    }

    auto stage = [&](int buf, int ph) {         // A0 8K + A1 8K + B 8K = 6 insts
        const uint32_t kb = (uint32_t)(ph << 13);   // (k>>5)<<13 with k=ph*32
        const char* sA0 = H + (size_t)s0 * H_SLOT_BYTES + kb;
        const char* sA1 = H + (size_t)(s0 + (two ? 1 : 0)) * H_SLOT_BYTES + kb;
        const char* sB  = Wp + w_tile_base(nt, pk0 + (ph >> 1)) + (uint32_t)((ph & 1) << 13);
        #pragma unroll
        for (int jj = 0; jj < 2; ++jj) {
            uint32_t o = (uint32_t)(jj << 12) + (uint32_t)(tid << 4);
            uint32_t d = (uint32_t)(jj << 12) + (uint32_t)(wv << 10);
            char* db = ldsAB + buf * 24576 + d;
            __builtin_amdgcn_global_load_lds(
                (const __attribute__((address_space(1))) void*)(sA0 + o),
                (__attribute__((address_space(3))) void*)(db), 16, 0, 0);
            __builtin_amdgcn_global_load_lds(
                (const __attribute__((address_space(1))) void*)(sA1 + o),
                (__attribute__((address_space(3))) void*)(db + 8192), 16, 0, 0);
            __builtin_amdgcn_global_load_lds(
                (const __attribute__((address_space(1))) void*)(sB + o),
                (__attribute__((address_space(3))) void*)(db + 16384), 16, 0, 0);
        }
    };

    f32x4 acc[2][4][4];
    #pragma unroll
    for (int g = 0; g < 2; ++g)
        #pragma unroll
        for (int m = 0; m < 4; ++m)
            #pragma unroll
            for (int n = 0; n < 4; ++n) acc[g][m][n] = (f32x4){0.f, 0.f, 0.f, 0.f};

    stage(0, 0);
    stage(1, 1);
    asm volatile("s_waitcnt vmcnt(6) lgkmcnt(0)" ::: "memory");
    __builtin_amdgcn_s_barrier();

    int cur = 0;
    #pragma unroll 1
    for (int ph = 0; ph < 64; ++ph) {
        int nxt2 = cur + 2; if (nxt2 >= 3) nxt2 -= 3;
        if (ph + 2 < 64) stage(nxt2, ph + 2);
        const char* lb = ldsAB + cur * 24576;
        f16x8 bf[4];
        #pragma unroll
        for (int nf = 0; nf < 4; ++nf) bf[nf] = *(const f16x8*)(lb + 16384 + boff[nf]);
        {
            f16x8 ah[4];
            #pragma unroll
            for (int m = 0; m < 4; ++m) ah[m] = *(const f16x8*)(lb + aoff[m]);
            #pragma unroll
            for (int m = 0; m < 4; ++m)
                #pragma unroll
                for (int nf = 0; nf < 4; ++nf)
                    acc[0][m][nf] = __builtin_amdgcn_mfma_f32_16x16x32_f16(ah[m], bf[nf], acc[0][m][nf], 0, 0, 0);
        }
        if (two) {
            f16x8 ah[4];
            #pragma unroll
            for (int m = 0; m < 4; ++m) ah[m] = *(const f16x8*)(lb + 8192 + aoff[m]);
            #pragma unroll
            for (int m = 0; m < 4; ++m)
                #pragma unroll
                for (int nf = 0; nf < 4; ++nf)
                    acc[1][m][nf] = __builtin_amdgcn_mfma_f32_16x16x32_f16(ah[m], bf[nf], acc[1][m][nf], 0, 0, 0);
        }
        if (ph + 1 < 64) {
            if (ph + 2 < 64) asm volatile("s_waitcnt vmcnt(6) lgkmcnt(0)" ::: "memory");
            else             asm volatile("s_waitcnt vmcnt(0) lgkmcnt(0)" ::: "memory");
            __builtin_amdgcn_s_barrier();
        }
        ++cur; if (cur == 3) cur = 0;
    }

    // C/D layout (verified R0-R15): col = lane&15, row = (lane>>4)*4 + reg
    const int r0 = (lane >> 4) << 2;
    #pragma unroll
    for (int g = 0; g < 2; ++g) {
        if (g == 1 && !two) break;
        int t = s0 + g - j;                     // step offset of this product
        int idx = t * 12 - t * (t - 1) / 2 + j; // t-major chunk index
        _Float16* pb = pF + (size_t)idx * (CH_BYTES / 2)
                     + ((size_t)((wr << 6) + r0)) * N_ + jbase;
        #pragma unroll
        for (int m = 0; m < 4; ++m)
            #pragma unroll
            for (int n = 0; n < 4; ++n)
                #pragma unroll
                for (int r = 0; r < 4; ++r)
                    pb[(size_t)(m * 16 + r) * N_ + n * 16] = (_Float16)acc[g][m][n][r];
    }
}

// ---------------- feedback step t: K = t*2048 over y-slots, 4t chunks ----------------
__global__ __launch_bounds__(256, 3) void gemm_FB(
        const char* __restrict__ Wp, const char* __restrict__ H,
        _Float16* __restrict__ pFB, int t)
{
    __shared__ alignas(16) char ldsAB[3 * 16384];
    int c = blockIdx.x >> 4, nt = blockIdx.x & 15;
    int j = c >> 2, sub = c & 3;
    int i = 12 - t + j;                         // W slice index in window
    gemm_body(Wp, H, pFB + (size_t)c * (CH_BYTES / 2), ldsAB,
              nt, i * 32 + sub * 8, 12 + j, sub * 512, 16);
}

// ---------------- reduce step t: y_{t+1} = sum F-chunks + scaled fb-chunks ----------------
__global__ void reduce_step(const _Float16* __restrict__ pF, const _Float16* __restrict__ pFB,
                            float* __restrict__ out, char* __restrict__ H, int t)
{
    int tid = blockIdx.x * 256 + threadIdx.x;   // 65536 threads: (b, n-quad)
    int b = tid >> 9;
    int n0 = (tid & 511) << 2;
    const size_t eo = (size_t)b * N_ + n0;
    float s0 = 0.f, s1 = 0.f, s2 = 0.f, s3 = 0.f;
    int baseT = t * 12 - t * (t - 1) / 2;
    int nF = 12 - t;
    #pragma unroll 4
    for (int f = 0; f < nF; ++f) {              // F chunks: scale 1 (x domain)
        F16x4v p;
        p.q = *(const uint2*)(pF + (size_t)(baseT + f) * (CH_BYTES / 2) + eo);
        s0 += (float)p.h[0]; s1 += (float)p.h[1];
        s2 += (float)p.h[2]; s3 += (float)p.h[3];
    }
    #pragma unroll 4
    for (int c = 0; c < 4 * t; ++c) {           // fb chunks: scale 2^E[j]
        float sc = pow2f(E_TAB[c >> 2]);
        F16x4v p;
        p.q = *(const uint2*)(pFB + (size_t)c * (CH_BYTES / 2) + eo);
        s0 += (float)p.h[0] * sc; s1 += (float)p.h[1] * sc;
        s2 += (float)p.h[2] * sc; s3 += (float)p.h[3] * sc;
    }
    float* ob = out + eo * P_ + t;
    ob[0 * P_] = s0; ob[1 * P_] = s1; ob[2 * P_] = s2; ob[3 * P_] = s3;
    if (t < 11) {                               // store y_{t+1} scaled by 2^-e
        float ds = pow2f(-E_TAB[t]);
        F16x4v o;
        o.h[0] = (_Float16)(s0 * ds); o.h[1] = (_Float16)(s1 * ds);
        o.h[2] = (_Float16)(s2 * ds); o.h[3] = (_Float16)(s3 * ds);
        *(uint2*)(H + h_off(12 + t, b, n0)) = o.q;   // 8B-aligned under swizzle
    }
}

// ---------------- insurance: naive fp32 path if workspace is too small ----------------
__global__ void naive_step(const float* __restrict__ x, const float* __restrict__ W,
                           float* __restrict__ out, int t)
{
    int tid = blockIdx.x * 256 + threadIdx.x;   // 262144 threads: (b, j)
    int b = tid >> 11;
    int j = tid & (N_ - 1);
    float acc = 0.f;
    for (int i = 0; i < 12; ++i) {
        int g = t + i;
        const float* src = (g < 12) ? (x   + (size_t)b * (N_ * 12) + g)
                                    : (out + (size_t)b * (N_ * 12) + (g - 12));
        const float* wr = W + ((size_t)i * N_ + j) * N_;
        for (int k = 0; k < N_; ++k)
            acc += wr[k] * src[(size_t)k * 12];
    }
    out[((size_t)b * N_ + j) * 12 + t] = acc;
}

extern "C" void kernel_launch(void* const* d_in, const int* in_sizes, int n_in,
                              void* d_out, int out_size, void* d_ws, size_t ws_size,
                              hipStream_t stream)
{
    const float* x = (const float*)d_in[0];
    const float* W = (const float*)d_in[1];
    float* out = (float*)d_out;

    if (ws_size < WS_NEEDED) {                  // fallback: correct but slow
        for (int t = 0; t < 12; ++t)
            naive_step<<<1024, 256, 0, stream>>>(x, W, out, t);
        return;
    }

    char* Wp = (char*)d_ws;
    char* H  = Wp + WPK_BYTES;
    _Float16* pF  = (_Float16*)(H + H_BYTES);
    _Float16* pFB = (_Float16*)(H + H_BYTES + PF_BYTES);

    prep_all<<<6272, 256, 0, stream>>>(x, W, Wp, H);
    gemm_F2<<<672, 256, 0, stream>>>(Wp, H, pF);
    reduce_step<<<256, 256, 0, stream>>>(pF, pFB, out, H, 0);
    for (int t = 1; t < 12; ++t) {
        gemm_FB<<<64 * t, 256, 0, stream>>>(Wp, H, pFB, t);
        reduce_step<<<256, 256, 0, stream>>>(pF, pFB, out, H, t);
    }
}